// Round 2
// baseline (665.257 us; speedup 1.0000x reference)
//
#include <hip/hip_runtime.h>
#include <hip/hip_bf16.h>
#include <type_traits>

#define NV 23
#define NTOT 16384
#define FLAT (NV * 256)    // 5888
#define FLAT4 (FLAT / 4)   // 1472
#define NB 32              // n per block

typedef short s16x8 __attribute__((ext_vector_type(8)));
typedef float f32x4 __attribute__((ext_vector_type(4)));
typedef unsigned u32x4 __attribute__((ext_vector_type(4)));

// x/23 for 0 <= x < 61681
__device__ __forceinline__ int divNV(int x) { return (int)(((unsigned)x * 45591u) >> 20); }
// f32 -> bf16 bits, RNE
__device__ __forceinline__ unsigned f2bf(float f) {
  unsigned u = __float_as_uint(f);
  u += 0x7fffu + ((u >> 16) & 1u);
  return u >> 16;
}

// ws layout (bytes): Wt@0 (131072) | tab@131072 (23552) | sum@154624 | ssq@178176
//                    | An2@201728 | Bn2@225280  -> 248832 total
__global__ void k_prep(const float* __restrict__ W, const float* __restrict__ mask,
                       short* __restrict__ Wt, unsigned* __restrict__ tab,
                       float* __restrict__ sums) {
  int idx = blockIdx.x * 256 + threadIdx.x;  // grid 256 -> 65536
  int d = idx >> 8, c = idx & 255;
  Wt[idx] = (short)f2bf(W[c * 256 + d]);     // W^T in bf16: Wt[d][c]
  if (idx < FLAT) {
    // p = idx = c*23 + v ; w = (v - c) mod 23 ; swizzled LDS byte offset
    int cc = divNV(idx);
    int v = idx - NV * cc;
    int cm = cc - NV * divNV(cc);
    int w = v - cm; w += (w >> 31) & NV;
    unsigned off = (unsigned)((w << 9) + ((cc << 1) ^ ((w & 7) << 4)));
    tab[idx] = (f2bf(tanhf(mask[(w << 8) + cc]) + 1.0f) << 16) | off;
  }
  if (idx < 2 * FLAT) sums[idx] = 0.0f;      // zero sum+ssq
}

__global__ void k_finalize(const float* __restrict__ sum, const float* __restrict__ ssq,
                           const float* __restrict__ bnw, const float* __restrict__ bnb,
                           float* __restrict__ An2, float* __restrict__ Bn2) {
  int idx = blockIdx.x * 256 + threadIdx.x;  // (w,d) feature in y-space
  if (idx >= FLAT) return;
  int w = idx >> 8, d = idx & 255;
  float mean = sum[idx] * (1.0f / NTOT);
  float var  = ssq[idx] * (1.0f / NTOT) - mean * mean;
  float inv  = rsqrtf(var + 1e-5f);
  int i = w + d; i -= NV * divNV(i);         // out-shift row i = (w+d) % 23
  float a = inv * bnw[i * 256 + d];
  An2[d * NV + i] = a;                       // j-indexed (flat out order)
  Bn2[d * NV + i] = bnb[i * 256 + d] - mean * a;
}

// WAVES=16/WRITE=0: stats pass (1024 thr).  WAVES=8/WRITE=1: output pass (512 thr).
template <int WAVES, int WRITE>
__global__ __launch_bounds__(WAVES * 64, 4) void k_gemm(
    const float* __restrict__ x0, const short* __restrict__ Wt,
    const unsigned* __restrict__ tab, float* __restrict__ sum, float* __restrict__ ssq,
    const float* __restrict__ An2, const float* __restrict__ Bn2,
    float* __restrict__ out) {
  constexpr int DW = 256 / WAVES;    // d per wave
  constexpr int NT = DW / 16;        // n-tiles per wave
  constexpr int CH = FLAT4 / WAVES;  // f32x4 chunk per wave (92 or 184)
  constexpr int NS = (CH + 63) / 64; // reg slots per chunk (2 or 3)
  extern __shared__ char smem[];     // Xb0@0, Xb1@16384, O@32768 (WRITE only)
  float* O = (float*)(smem + 32768);

  const int tid = threadIdx.x;
  const int lane = tid & 63;
  const int wv = tid >> 6;
  const int l15 = lane & 15;
  const int lg = lane >> 4;
  const int d0 = wv * DW;
  const int ch0 = wv * CH;

  // B fragments, register-resident: B[k=c][n=d] = Wt[d][c]
  s16x8 bfr[NT][8];
#pragma unroll
  for (int nt = 0; nt < NT; ++nt)
#pragma unroll
    for (int kt = 0; kt < 8; ++kt)
      bfr[nt][kt] = *(const s16x8*)(Wt + (d0 + nt * 16 + l15) * 256 + kt * 32 + lg * 8);

  // formation table, register-resident (n-invariant)
  u32x4 tbr[NS];
#pragma unroll
  for (int s = 0; s < NS; ++s)
    if (s * 64 + lane < CH) tbr[s] = *(const u32x4*)(tab + 4 * (ch0 + s * 64 + lane));

  // zero pad rows 23..31 of both X' buffers (never written again)
  for (int i = tid; i < 2304; i += WAVES * 64) {
    int b = i >= 1152;
    *(int*)(smem + b * 16384 + 11776 + (i - b * 1152) * 4) = 0;
  }

  f32x4 acc[2][NT];
  float s1[2][NT][4], s2[2][NT][4];
  if (!WRITE) {
#pragma unroll
    for (int mt = 0; mt < 2; ++mt)
#pragma unroll
      for (int nt = 0; nt < NT; ++nt)
#pragma unroll
        for (int r = 0; r < 4; ++r) { s1[mt][nt][r] = 0.f; s2[mt][nt][r] = 0.f; }
  }

  const int nbase = blockIdx.x * NB;
  f32x4 xr[2][NS];  // 2-deep register prefetch of x0 slabs (compile-time slot index!)

  auto loadx = [&](auto SL, int T) {
    const f32x4* xg = (const f32x4*)(x0 + (size_t)(nbase + T) * FLAT);
#pragma unroll
    for (int s = 0; s < NS; ++s)
      if (s * 64 + lane < CH) xr[SL.value][s] = xg[ch0 + s * 64 + lane];
  };
  auto form = [&](auto SL) {  // X' formation into Xb[SL] from xr[SL]
    char* xb = smem + SL.value * 16384;
#pragma unroll
    for (int s = 0; s < NS; ++s)
      if (s * 64 + lane < CH) {
        u32x4 tb = tbr[s];
        f32x4 xv = xr[SL.value][s];
#pragma unroll
        for (int e = 0; e < 4; ++e) {
          unsigned tt = tb[e];
          *(short*)(xb + (tt & 0xffffu)) =
              (short)f2bf(xv[e] * __uint_as_float(tt & 0xffff0000u));
        }
      }
  };
  auto mstep = [&](auto BUF) {  // y = X' * W on Xb[BUF]
    const char* xb = smem + BUF.value * 16384;
#pragma unroll
    for (int kt = 0; kt < 8; ++kt) {
      s16x8 af[2];
#pragma unroll
      for (int mt = 0; mt < 2; ++mt) {
        int row = mt * 16 + l15;
        af[mt] = *(const s16x8*)(xb + (row << 9) +
                                 (((kt * 32 + lg * 8) << 1) ^ ((row & 7) << 4)));
      }
#pragma unroll
      for (int mt = 0; mt < 2; ++mt)
#pragma unroll
        for (int nt = 0; nt < NT; ++nt)
          acc[mt][nt] = __builtin_amdgcn_mfma_f32_16x16x32_bf16(
              af[mt], bfr[nt][kt], acc[mt][nt], 0, 0, 0);
    }
  };
  auto sstep = [&]() {
#pragma unroll
    for (int mt = 0; mt < 2; ++mt)
#pragma unroll
      for (int nt = 0; nt < NT; ++nt)
#pragma unroll
        for (int r = 0; r < 4; ++r) {
          float y = acc[mt][nt][r];
          s1[mt][nt][r] += y;
          s2[mt][nt][r] += y * y;
        }
  };
  auto wstep = [&](auto CUR, int T) {
    // scatter y -> O at out-shifted j = d*23 + (w+d)%23 (wave-local region!)
#pragma unroll
    for (int mt = 0; mt < 2; ++mt)
#pragma unroll
      for (int nt = 0; nt < NT; ++nt)
#pragma unroll
        for (int r = 0; r < 4; ++r) {
          int w = mt * 16 + lg * 4 + r;  // C/D: row = (lane>>4)*4 + reg
          if (w < NV) {
            int d = d0 + nt * 16 + l15;  // col = lane & 15
            int sj = w + d; sj -= NV * divNV(sj);
            O[d * NV + sj] = acc[mt][nt][r];
          }
        }
    // same-wave read-back (no barrier): normalize + residual(from regs) + relu
    float* og = out + (size_t)(nbase + T) * FLAT;
#pragma unroll
    for (int s = 0; s < NS; ++s)
      if (s * 64 + lane < CH) {
        int i = ch0 + s * 64 + lane;
        f32x4 y = *(const f32x4*)(O + 4 * i);
        f32x4 av = *(const f32x4*)(An2 + 4 * i);
        f32x4 bv = *(const f32x4*)(Bn2 + 4 * i);
        f32x4 o;
#pragma unroll
        for (int e = 0; e < 4; ++e)
          o[e] = fmaxf(fmaf(y[e], av[e], bv[e]) + xr[CUR.value][s][e], 0.0f);
        __builtin_nontemporal_store(o, (f32x4*)og + i);
      }
  };
  auto bar = []() {  // LDS-drain barrier: does NOT drain vmcnt (prefetch survives)
    asm volatile("s_waitcnt lgkmcnt(0)" ::: "memory");
    __builtin_amdgcn_s_barrier();
    asm volatile("" ::: "memory");
  };

  using I0 = std::integral_constant<int, 0>;
  using I1 = std::integral_constant<int, 1>;

  // prologue
  loadx(I0{}, 0);
  form(I0{});
  loadx(I1{}, 1);
  bar();

  for (int t = 0; t < NB; t += 2) {
    // ---- even n: consume Xb[0] ----
#pragma unroll
    for (int mt = 0; mt < 2; ++mt)
#pragma unroll
      for (int nt = 0; nt < NT; ++nt) acc[mt][nt] = (f32x4){0.f, 0.f, 0.f, 0.f};
    mstep(I0{});
    form(I1{});                       // t+1 < NB always here
    if (!WRITE) sstep(); else wstep(I0{}, t);
    if (t + 2 < NB) loadx(I0{}, t + 2);
    bar();
    // ---- odd n: consume Xb[1] ----
#pragma unroll
    for (int mt = 0; mt < 2; ++mt)
#pragma unroll
      for (int nt = 0; nt < NT; ++nt) acc[mt][nt] = (f32x4){0.f, 0.f, 0.f, 0.f};
    mstep(I1{});
    if (t + 2 < NB) form(I0{});
    if (!WRITE) sstep(); else wstep(I1{}, t + 1);
    if (t + 3 < NB) loadx(I1{}, t + 3);
    bar();
  }

  if (!WRITE) {
#pragma unroll
    for (int mt = 0; mt < 2; ++mt)
#pragma unroll
      for (int nt = 0; nt < NT; ++nt)
#pragma unroll
        for (int r = 0; r < 4; ++r) {
          int w = mt * 16 + lg * 4 + r;
          if (w < NV) {
            int d = d0 + nt * 16 + l15;
            atomicAdd(sum + (w << 8) + d, s1[mt][nt][r]);
            atomicAdd(ssq + (w << 8) + d, s2[mt][nt][r]);
          }
        }
  }
}

extern "C" void kernel_launch(void* const* d_in, const int* in_sizes, int n_in,
                              void* d_out, int out_size, void* d_ws, size_t ws_size,
                              hipStream_t stream) {
  const float* x0   = (const float*)d_in[0];
  const float* W    = (const float*)d_in[1];
  // d_in[2] = bias: cancels inside BN -> unused
  const float* mask = (const float*)d_in[3];
  const float* bnw  = (const float*)d_in[4];
  const float* bnb  = (const float*)d_in[5];
  // d_in[6], d_in[7] = shift tables: folded into addressing
  float* out = (float*)d_out;

  char* ws = (char*)d_ws;
  short* Wt     = (short*)ws;
  unsigned* tab = (unsigned*)(ws + 131072);
  float* sum    = (float*)(ws + 154624);
  float* ssq    = (float*)(ws + 178176);
  float* An2    = (float*)(ws + 201728);
  float* Bn2    = (float*)(ws + 225280);

  k_prep<<<256, 256, 0, stream>>>(W, mask, Wt, tab, sum);
  k_gemm<16, 0><<<512, 1024, 32768, stream>>>(x0, Wt, tab, sum, ssq, nullptr, nullptr, nullptr);
  k_finalize<<<23, 256, 0, stream>>>(sum, ssq, bnw, bnb, An2, Bn2);
  k_gemm<8, 1><<<512, 512, 56320, stream>>>(x0, Wt, tab, sum, ssq, An2, Bn2, out);
}

// Round 3
// 298.966 us; speedup vs baseline: 2.2252x; 2.2252x over previous
//
#include <hip/hip_runtime.h>
#include <hip/hip_bf16.h>
#include <type_traits>

#define NV 23
#define NTOT 16384
#define FLAT (NV * 256)    // 5888
#define FLAT4 (FLAT / 4)   // 1472
#define NB 32              // n per block
#define WAVES 16
#define CH (FLAT4 / WAVES) // 92 f32x4 per wave
#define NS 2               // ceil(92/64) reg slots

typedef short s16x8 __attribute__((ext_vector_type(8)));
typedef float f32x4 __attribute__((ext_vector_type(4)));
typedef unsigned u32x4 __attribute__((ext_vector_type(4)));

// x/23 for 0 <= x < 61681
__device__ __forceinline__ int divNV(int x) { return (int)(((unsigned)x * 45591u) >> 20); }
// f32 -> bf16 bits, RNE
__device__ __forceinline__ unsigned f2bf(float f) {
  unsigned u = __float_as_uint(f);
  u += 0x7fffu + ((u >> 16) & 1u);
  return u >> 16;
}

// ws layout (bytes): Wt@0 (131072) | tab@131072 (23552) | sum@154624 | ssq@178176
//                    | An2@201728 | Bn2@225280  -> 248832 total
__global__ void k_prep(const float* __restrict__ W, const float* __restrict__ mask,
                       short* __restrict__ Wt, unsigned* __restrict__ tab,
                       float* __restrict__ sums) {
  int idx = blockIdx.x * 256 + threadIdx.x;  // grid 256 -> 65536
  int d = idx >> 8, c = idx & 255;
  Wt[idx] = (short)f2bf(W[c * 256 + d]);     // W^T in bf16: Wt[d][c]
  if (idx < FLAT) {
    // p = idx = c*23 + v ; w = (v - c) mod 23 ; swizzled LDS byte offset
    int cc = divNV(idx);
    int v = idx - NV * cc;
    int cm = cc - NV * divNV(cc);
    int w = v - cm; w += (w >> 31) & NV;
    unsigned off = (unsigned)((w << 9) + ((cc << 1) ^ ((w & 7) << 4)));
    tab[idx] = (f2bf(tanhf(mask[(w << 8) + cc]) + 1.0f) << 16) | off;
  }
  if (idx < 2 * FLAT) sums[idx] = 0.0f;      // zero sum+ssq
}

__global__ void k_finalize(const float* __restrict__ sum, const float* __restrict__ ssq,
                           const float* __restrict__ bnw, const float* __restrict__ bnb,
                           float* __restrict__ An2, float* __restrict__ Bn2) {
  int idx = blockIdx.x * 256 + threadIdx.x;  // (w,d) feature in y-space
  if (idx >= FLAT) return;
  int w = idx >> 8, d = idx & 255;
  float mean = sum[idx] * (1.0f / NTOT);
  float var  = ssq[idx] * (1.0f / NTOT) - mean * mean;
  float inv  = rsqrtf(var + 1e-5f);
  int i = w + d; i -= NV * divNV(i);         // out-shift row i = (w+d) % 23
  float a = inv * bnw[i * 256 + d];
  An2[d * NV + i] = a;                       // j-indexed (flat out order)
  Bn2[d * NV + i] = bnb[i * 256 + d] - mean * a;
}

// WRITE=0: stats pass.  WRITE=1: recompute + normalize + residual + relu.
// 16 waves x 64; each wave owns d-strip [wv*16, wv*16+16) and slab chunk
// [wv*CH, (wv+1)*CH) f32x4 == exactly that d-strip's flat out region.
template <int WRITE>
__global__ __launch_bounds__(1024, 4) void k_gemm(
    const float* __restrict__ x0, const short* __restrict__ Wt,
    const unsigned* __restrict__ tab, float* __restrict__ sum, float* __restrict__ ssq,
    const float* __restrict__ An2, const float* __restrict__ Bn2,
    float* __restrict__ out) {
  extern __shared__ char smem[];     // Xb0@0, Xb1@16384, O@32768 (WRITE only)
  float* O = (float*)(smem + 32768);

  const int tid = threadIdx.x;
  const int lane = tid & 63;
  const int wv = tid >> 6;
  const int l15 = lane & 15;
  const int lg = lane >> 4;
  const int d0 = wv * 16;
  const int ch0 = wv * CH;

  // B fragments, register-resident (32 VGPR): B[k=c][n=d] = Wt[d][c]
  s16x8 bfr[8];
#pragma unroll
  for (int kt = 0; kt < 8; ++kt)
    bfr[kt] = *(const s16x8*)(Wt + (d0 + l15) * 256 + kt * 32 + lg * 8);

  // formation table, register-resident (n-invariant)
  u32x4 tbr[NS];
#pragma unroll
  for (int s = 0; s < NS; ++s)
    if (s * 64 + lane < CH) tbr[s] = *(const u32x4*)(tab + 4 * (ch0 + s * 64 + lane));

  // BN affine tables, register-resident (n-invariant), WRITE only
  f32x4 anr[NS], bnr[NS];
  if (WRITE) {
#pragma unroll
    for (int s = 0; s < NS; ++s)
      if (s * 64 + lane < CH) {
        anr[s] = *(const f32x4*)(An2 + 4 * (ch0 + s * 64 + lane));
        bnr[s] = *(const f32x4*)(Bn2 + 4 * (ch0 + s * 64 + lane));
      }
  }

  // zero pad rows 23..31 of both X' buffers (never written again)
  for (int i = tid; i < 2304; i += 1024) {
    int b = i >= 1152;
    *(int*)(smem + b * 16384 + 11776 + (i - b * 1152) * 4) = 0;
  }

  f32x4 acc[2];
  float s1[2][4], s2[2][4];
  if (!WRITE) {
#pragma unroll
    for (int mt = 0; mt < 2; ++mt)
#pragma unroll
      for (int r = 0; r < 4; ++r) { s1[mt][r] = 0.f; s2[mt][r] = 0.f; }
  }

  const int nbase = blockIdx.x * NB;
  f32x4 xr[2][NS];  // 2-deep register prefetch of x0 slabs

  auto loadx = [&](auto SL, int T) {
    const f32x4* xg = (const f32x4*)(x0 + (size_t)(nbase + T) * FLAT);
#pragma unroll
    for (int s = 0; s < NS; ++s)
      if (s * 64 + lane < CH) xr[SL.value][s] = xg[ch0 + s * 64 + lane];
  };
  auto form = [&](auto SL) {  // X' formation into Xb[SL] from xr[SL]
    char* xb = smem + SL.value * 16384;
#pragma unroll
    for (int s = 0; s < NS; ++s)
      if (s * 64 + lane < CH) {
        u32x4 tb = tbr[s];
        f32x4 xv = xr[SL.value][s];
#pragma unroll
        for (int e = 0; e < 4; ++e) {
          unsigned tt = tb[e];
          *(short*)(xb + (tt & 0xffffu)) =
              (short)f2bf(xv[e] * __uint_as_float(tt & 0xffff0000u));
        }
      }
  };
  auto mstep = [&](auto BUF) {  // y = X' * W on Xb[BUF]
    const char* xb = smem + BUF.value * 16384;
#pragma unroll
    for (int kt = 0; kt < 8; ++kt) {
      s16x8 af[2];
#pragma unroll
      for (int mt = 0; mt < 2; ++mt) {
        int row = mt * 16 + l15;
        af[mt] = *(const s16x8*)(xb + (row << 9) +
                                 (((kt * 32 + lg * 8) << 1) ^ ((row & 7) << 4)));
      }
#pragma unroll
      for (int mt = 0; mt < 2; ++mt)
        acc[mt] = __builtin_amdgcn_mfma_f32_16x16x32_bf16(af[mt], bfr[kt], acc[mt], 0, 0, 0);
    }
  };
  auto sstep = [&]() {
#pragma unroll
    for (int mt = 0; mt < 2; ++mt)
#pragma unroll
      for (int r = 0; r < 4; ++r) {
        float y = acc[mt][r];
        s1[mt][r] += y;
        s2[mt][r] += y * y;
      }
  };
  auto wstep = [&](auto CUR, int T) {
    // scatter y -> O at out-shifted j = d*23 + (w+d)%23 (wave-local region!)
#pragma unroll
    for (int mt = 0; mt < 2; ++mt)
#pragma unroll
      for (int r = 0; r < 4; ++r) {
        int w = mt * 16 + lg * 4 + r;  // C/D: row = (lane>>4)*4 + reg
        if (w < NV) {
          int d = d0 + l15;            // col = lane & 15
          int sj = w + d; sj -= NV * divNV(sj);
          O[d * NV + sj] = acc[mt][r];
        }
      }
    // same-wave read-back (no barrier): normalize + residual(from regs) + relu
    float* og = out + (size_t)(nbase + T) * FLAT;
#pragma unroll
    for (int s = 0; s < NS; ++s)
      if (s * 64 + lane < CH) {
        int i = ch0 + s * 64 + lane;
        f32x4 y = *(const f32x4*)(O + 4 * i);
        f32x4 o;
#pragma unroll
        for (int e = 0; e < 4; ++e)
          o[e] = fmaxf(fmaf(y[e], anr[s][e], bnr[s][e]) + xr[CUR.value][s][e], 0.0f);
        __builtin_nontemporal_store(o, (f32x4*)og + i);
      }
  };
  auto bar = []() {  // LDS-drain barrier: does NOT drain vmcnt (prefetch survives)
    asm volatile("s_waitcnt lgkmcnt(0)" ::: "memory");
    __builtin_amdgcn_s_barrier();
    asm volatile("" ::: "memory");
  };

  using I0 = std::integral_constant<int, 0>;
  using I1 = std::integral_constant<int, 1>;

  // prologue
  loadx(I0{}, 0);
  form(I0{});
  loadx(I1{}, 1);
  bar();

  for (int t = 0; t < NB; t += 2) {
    // ---- even n: consume Xb[0] ----
#pragma unroll
    for (int mt = 0; mt < 2; ++mt) acc[mt] = (f32x4){0.f, 0.f, 0.f, 0.f};
    mstep(I0{});
    form(I1{});
    if (!WRITE) sstep(); else wstep(I0{}, t);
    if (t + 2 < NB) loadx(I0{}, t + 2);
    bar();
    // ---- odd n: consume Xb[1] ----
#pragma unroll
    for (int mt = 0; mt < 2; ++mt) acc[mt] = (f32x4){0.f, 0.f, 0.f, 0.f};
    mstep(I1{});
    if (t + 2 < NB) form(I0{});
    if (!WRITE) sstep(); else wstep(I1{}, t + 1);
    if (t + 3 < NB) loadx(I1{}, t + 3);
    bar();
  }

  if (!WRITE) {
#pragma unroll
    for (int mt = 0; mt < 2; ++mt)
#pragma unroll
      for (int r = 0; r < 4; ++r) {
        int w = mt * 16 + lg * 4 + r;
        if (w < NV) {
          int d = d0 + l15;
          atomicAdd(sum + (w << 8) + d, s1[mt][r]);
          atomicAdd(ssq + (w << 8) + d, s2[mt][r]);
        }
      }
  }
}

extern "C" void kernel_launch(void* const* d_in, const int* in_sizes, int n_in,
                              void* d_out, int out_size, void* d_ws, size_t ws_size,
                              hipStream_t stream) {
  const float* x0   = (const float*)d_in[0];
  const float* W    = (const float*)d_in[1];
  // d_in[2] = bias: cancels inside BN -> unused
  const float* mask = (const float*)d_in[3];
  const float* bnw  = (const float*)d_in[4];
  const float* bnb  = (const float*)d_in[5];
  // d_in[6], d_in[7] = shift tables: folded into addressing
  float* out = (float*)d_out;

  char* ws = (char*)d_ws;
  short* Wt     = (short*)ws;
  unsigned* tab = (unsigned*)(ws + 131072);
  float* sum    = (float*)(ws + 154624);
  float* ssq    = (float*)(ws + 178176);
  float* An2    = (float*)(ws + 201728);
  float* Bn2    = (float*)(ws + 225280);

  k_prep<<<256, 256, 0, stream>>>(W, mask, Wt, tab, sum);
  k_gemm<0><<<512, 1024, 32768, stream>>>(x0, Wt, tab, sum, ssq, nullptr, nullptr, nullptr);
  k_finalize<<<23, 256, 0, stream>>>(sum, ssq, bnw, bnb, An2, Bn2);
  k_gemm<1><<<512, 1024, 56320, stream>>>(x0, Wt, tab, sum, ssq, An2, Bn2, out);
}